// Round 12
// baseline (49.669 us; speedup 1.0000x reference)
//
#include <hip/hip_runtime.h>

static constexpr int kNodes  = 100000;
static constexpr int kEdges  = 1600000;
static constexpr int kPairs  = kEdges / 2;
static constexpr int kD      = 128;
static constexpr int kGroups = kNodes / 4;   // 25000 groups of 4 consecutive nodes

typedef float              fx4 __attribute__((ext_vector_type(4)));
typedef unsigned long long u64;

// ---------------------------------------------------------------------------
// Phase 1: per-node difference dots, 4 consecutive nodes per 16-lane group.
//   u[n] = emb[n]·(W1-W0)[0:128], v[n] = emb[n]·(W1-W0)[128:256]
// All 8 emb fx4-loads issued back-to-back (4x memory parallelism vs R7) before
// any compute; W regs amortized over 4 nodes; lane0 packs (u,v) pairs for all
// 4 nodes and writes uv[8g..8g+8) as two fx4 stores.
// Launched 3x this round (idempotent) to measure T_node from dur delta.
// ---------------------------------------------------------------------------
__global__ __launch_bounds__(256) void node_pre(const float* __restrict__ emb,
                                                const float* __restrict__ W,
                                                float* __restrict__ uv) {
    const int l  = threadIdx.x & 15;   // lane within 16-group
    const int c0 = l * 8;

    fx4 w0a = *(const fx4*)&W[c0],       w0b = *(const fx4*)&W[c0 + 4];
    fx4 w1a = *(const fx4*)&W[256 + c0], w1b = *(const fx4*)&W[256 + c0 + 4];
    fx4 dua = w1a - w0a, dub = w1b - w0b;
    fx4 w2a = *(const fx4*)&W[128 + c0], w2b = *(const fx4*)&W[128 + c0 + 4];
    fx4 w3a = *(const fx4*)&W[384 + c0], w3b = *(const fx4*)&W[384 + c0 + 4];
    fx4 dva = w3a - w2a, dvb = w3b - w2b;

    const int g = (blockIdx.x * blockDim.x + threadIdx.x) >> 4;
    if (g >= kGroups) return;
    const int n0 = g * 4;

    // batched loads: 8 independent fx4 loads in flight
    fx4 ea0, eb0, ea1, eb1, ea2, eb2, ea3, eb3;
    {
        const float* base = emb + (size_t)n0 * kD + c0;
        ea0 = *(const fx4*)(base);
        eb0 = *(const fx4*)(base + 4);
        ea1 = *(const fx4*)(base + kD);
        eb1 = *(const fx4*)(base + kD + 4);
        ea2 = *(const fx4*)(base + 2 * kD);
        eb2 = *(const fx4*)(base + 2 * kD + 4);
        ea3 = *(const fx4*)(base + 3 * kD);
        eb3 = *(const fx4*)(base + 3 * kD + 4);
    }

    fx4 pair01, pair23;   // lane0: {u0,v0,u1,v1}, {u2,v2,u3,v3}

#define DO_NODE(EA, EB, SLOT0, SLOT1, PAIR)                                   \
    {                                                                         \
        float pu = EA.x*dua.x + EA.y*dua.y + EA.z*dua.z + EA.w*dua.w          \
                 + EB.x*dub.x + EB.y*dub.y + EB.z*dub.z + EB.w*dub.w;         \
        float pv = EA.x*dva.x + EA.y*dva.y + EA.z*dva.z + EA.w*dva.w          \
                 + EB.x*dvb.x + EB.y*dvb.y + EB.z*dvb.z + EB.w*dvb.w;         \
        float keep = (l & 1) ? pv : pu;                                       \
        float send = (l & 1) ? pu : pv;                                       \
        float x = keep + __shfl_xor(send, 1);                                 \
        x += __shfl_xor(x, 2);                                                \
        x += __shfl_xor(x, 4);                                                \
        x += __shfl_xor(x, 8);                                                \
        float other = __shfl_xor(x, 1);  /* lane0: v_j */                     \
        PAIR.SLOT0 = x;                                                       \
        PAIR.SLOT1 = other;                                                   \
    }

    DO_NODE(ea0, eb0, x, y, pair01)
    DO_NODE(ea1, eb1, z, w, pair01)
    DO_NODE(ea2, eb2, x, y, pair23)
    DO_NODE(ea3, eb3, z, w, pair23)
#undef DO_NODE

    if (l == 0) {
        ((fx4*)uv)[g * 2]     = pair01;   // uv[8g .. 8g+4)
        ((fx4*)uv)[g * 2 + 1] = pair23;   // uv[8g+4 .. 8g+8)
    }
}

// ---------------------------------------------------------------------------
// Phase 2: exact R7 edge kernel. 2 edges/thread, interleaved uv gathers,
// d = u[r]+v[c]+db, p0 = 1/(1+e^d).
// ---------------------------------------------------------------------------
__global__ __launch_bounds__(256) void edge_attn(const void* __restrict__ eiv,
                                                 const float* __restrict__ uv,
                                                 const float* __restrict__ b,
                                                 float* __restrict__ out) {
    const u64* ei64 = (const u64*)eiv;
    u64 hi = ei64[threadIdx.x & 63] >> 32;
    const bool is64 = (__ballot(hi != 0ull) == 0ull);

    const int e2 = blockIdx.x * blockDim.x + threadIdx.x;   // pair index
    if (e2 >= kPairs) return;

    int r0, r1, c0i, c1i;
    if (is64) {
        const u64* rr = ei64 + 2 * e2;
        const u64* cc = ei64 + kEdges + 2 * e2;
        r0  = (int)rr[0]; r1  = (int)rr[1];
        c0i = (int)cc[0]; c1i = (int)cc[1];
    } else {
        const int* ei32 = (const int*)eiv;
        r0  = ei32[2 * e2];          r1  = ei32[2 * e2 + 1];
        c0i = ei32[kEdges + 2 * e2]; c1i = ei32[kEdges + 2 * e2 + 1];
    }

    const float db = b[1] - b[0];

    float d0 = uv[2 * r0] + uv[2 * c0i + 1] + db;
    float d1 = uv[2 * r1] + uv[2 * c1i + 1] + db;

    float p00 = __builtin_amdgcn_rcpf(1.0f + __expf(d0));
    float p10 = __builtin_amdgcn_rcpf(1.0f + __expf(d1));

    fx4 o = {p00, 1.0f - p00, p10, 1.0f - p10};
    ((fx4*)out)[e2] = o;
}

extern "C" void kernel_launch(void* const* d_in, const int* in_sizes, int n_in,
                              void* d_out, int out_size, void* d_ws, size_t ws_size,
                              hipStream_t stream) {
    const float* emb = (const float*)d_in[0];
    const void*  ei  = d_in[1];
    const float* W   = (const float*)d_in[2];
    const float* b   = (const float*)d_in[3];
    float* out = (float*)d_out;

    float* uv = (float*)d_ws;   // 800 KB node table

    const int nb = (kGroups * 16 + 255) / 256;
    // node_pre launched 3x (idempotent): measures T_node via dur delta.
    node_pre<<<nb, 256, 0, stream>>>(emb, W, uv);
    node_pre<<<nb, 256, 0, stream>>>(emb, W, uv);
    node_pre<<<nb, 256, 0, stream>>>(emb, W, uv);

    edge_attn<<<(kPairs + 255) / 256, 256, 0, stream>>>(ei, uv, b, out);
}

// Round 13
// 31.348 us; speedup vs baseline: 1.5844x; 1.5844x over previous
//
#include <hip/hip_runtime.h>

static constexpr int kNodes  = 100000;
static constexpr int kEdges  = 1600000;
static constexpr int kPairs  = kEdges / 2;
static constexpr int kD      = 128;
static constexpr int kGroups = kNodes / 4;   // 25000 groups of 4 consecutive nodes

typedef float              fx4 __attribute__((ext_vector_type(4)));
typedef unsigned long long u64;

// ---------------------------------------------------------------------------
// Phase 1: per-node difference dots, 4 consecutive nodes per 16-lane group.
//   u[n] = emb[n]·(W1-W0)[0:128], v[n] = emb[n]·(W1-W0)[128:256]
// All 8 emb fx4-loads issued back-to-back (4x memory parallelism); W regs
// amortized over 4 nodes; lane0 packs (u,v) for all 4 nodes, two fx4 stores.
// Measured ~10.5 us (R12 3x-launch measurement) vs 7.8 us stream floor.
// ---------------------------------------------------------------------------
__global__ __launch_bounds__(256) void node_pre(const float* __restrict__ emb,
                                                const float* __restrict__ W,
                                                float* __restrict__ uv) {
    const int l  = threadIdx.x & 15;   // lane within 16-group
    const int c0 = l * 8;

    fx4 w0a = *(const fx4*)&W[c0],       w0b = *(const fx4*)&W[c0 + 4];
    fx4 w1a = *(const fx4*)&W[256 + c0], w1b = *(const fx4*)&W[256 + c0 + 4];
    fx4 dua = w1a - w0a, dub = w1b - w0b;
    fx4 w2a = *(const fx4*)&W[128 + c0], w2b = *(const fx4*)&W[128 + c0 + 4];
    fx4 w3a = *(const fx4*)&W[384 + c0], w3b = *(const fx4*)&W[384 + c0 + 4];
    fx4 dva = w3a - w2a, dvb = w3b - w2b;

    const int g = (blockIdx.x * blockDim.x + threadIdx.x) >> 4;
    if (g >= kGroups) return;
    const int n0 = g * 4;

    // batched loads: 8 independent fx4 loads in flight
    fx4 ea0, eb0, ea1, eb1, ea2, eb2, ea3, eb3;
    {
        const float* base = emb + (size_t)n0 * kD + c0;
        ea0 = *(const fx4*)(base);
        eb0 = *(const fx4*)(base + 4);
        ea1 = *(const fx4*)(base + kD);
        eb1 = *(const fx4*)(base + kD + 4);
        ea2 = *(const fx4*)(base + 2 * kD);
        eb2 = *(const fx4*)(base + 2 * kD + 4);
        ea3 = *(const fx4*)(base + 3 * kD);
        eb3 = *(const fx4*)(base + 3 * kD + 4);
    }

    fx4 pair01, pair23;   // lane0: {u0,v0,u1,v1}, {u2,v2,u3,v3}

#define DO_NODE(EA, EB, SLOT0, SLOT1, PAIR)                                   \
    {                                                                         \
        float pu = EA.x*dua.x + EA.y*dua.y + EA.z*dua.z + EA.w*dua.w          \
                 + EB.x*dub.x + EB.y*dub.y + EB.z*dub.z + EB.w*dub.w;         \
        float pv = EA.x*dva.x + EA.y*dva.y + EA.z*dva.z + EA.w*dva.w          \
                 + EB.x*dvb.x + EB.y*dvb.y + EB.z*dvb.z + EB.w*dvb.w;         \
        float keep = (l & 1) ? pv : pu;                                       \
        float send = (l & 1) ? pu : pv;                                       \
        float x = keep + __shfl_xor(send, 1);                                 \
        x += __shfl_xor(x, 2);                                                \
        x += __shfl_xor(x, 4);                                                \
        x += __shfl_xor(x, 8);                                                \
        float other = __shfl_xor(x, 1);  /* lane0: v_j */                     \
        PAIR.SLOT0 = x;                                                       \
        PAIR.SLOT1 = other;                                                   \
    }

    DO_NODE(ea0, eb0, x, y, pair01)
    DO_NODE(ea1, eb1, z, w, pair01)
    DO_NODE(ea2, eb2, x, y, pair23)
    DO_NODE(ea3, eb3, z, w, pair23)
#undef DO_NODE

    if (l == 0) {
        ((fx4*)uv)[g * 2]     = pair01;   // uv[8g .. 8g+4)
        ((fx4*)uv)[g * 2 + 1] = pair23;   // uv[8g+4 .. 8g+8)
    }
}

// ---------------------------------------------------------------------------
// Phase 2: R7 edge kernel (measured ~13.7 us ≈ combined HBM-stream + L2
// gather-line roofline). 2 edges/thread; d = u[r]+v[c]+db; p = 1/(1+e^d).
// ---------------------------------------------------------------------------
__global__ __launch_bounds__(256) void edge_attn(const void* __restrict__ eiv,
                                                 const float* __restrict__ uv,
                                                 const float* __restrict__ b,
                                                 float* __restrict__ out) {
    const u64* ei64 = (const u64*)eiv;
    u64 hi = ei64[threadIdx.x & 63] >> 32;
    const bool is64 = (__ballot(hi != 0ull) == 0ull);

    const int e2 = blockIdx.x * blockDim.x + threadIdx.x;   // pair index
    if (e2 >= kPairs) return;

    int r0, r1, c0i, c1i;
    if (is64) {
        const u64* rr = ei64 + 2 * e2;
        const u64* cc = ei64 + kEdges + 2 * e2;
        r0  = (int)rr[0]; r1  = (int)rr[1];
        c0i = (int)cc[0]; c1i = (int)cc[1];
    } else {
        const int* ei32 = (const int*)eiv;
        r0  = ei32[2 * e2];          r1  = ei32[2 * e2 + 1];
        c0i = ei32[kEdges + 2 * e2]; c1i = ei32[kEdges + 2 * e2 + 1];
    }

    const float db = b[1] - b[0];

    float d0 = uv[2 * r0] + uv[2 * c0i + 1] + db;
    float d1 = uv[2 * r1] + uv[2 * c1i + 1] + db;

    float p00 = __builtin_amdgcn_rcpf(1.0f + __expf(d0));
    float p10 = __builtin_amdgcn_rcpf(1.0f + __expf(d1));

    fx4 o = {p00, 1.0f - p00, p10, 1.0f - p10};
    ((fx4*)out)[e2] = o;
}

extern "C" void kernel_launch(void* const* d_in, const int* in_sizes, int n_in,
                              void* d_out, int out_size, void* d_ws, size_t ws_size,
                              hipStream_t stream) {
    const float* emb = (const float*)d_in[0];
    const void*  ei  = d_in[1];
    const float* W   = (const float*)d_in[2];
    const float* b   = (const float*)d_in[3];
    float* out = (float*)d_out;

    float* uv = (float*)d_ws;   // 800 KB node table

    node_pre<<<(kGroups * 16 + 255) / 256, 256, 0, stream>>>(emb, W, uv);
    edge_attn<<<(kPairs + 255) / 256, 256, 0, stream>>>(ei, uv, b, out);
}